// Round 1
// 249.080 us; speedup vs baseline: 2.5219x; 2.5219x over previous
//
#include <hip/hip_runtime.h>
#include <math.h>

#define NB 65536
#define DIM 256

// Staged-W geometry (fp16, padded-linear k-rows).
// ROWB = 264 halves = 528 B = 33*16B: ds_read_b128-aligned, start banks spread
// uniformly across lanes (8 lanes per 16B slot = structural minimum).
#define ROWB   528              // bytes per k-row (K=256 halves + 8 pad halves)
#define ESEC   18432            // bytes per expert section: 32*528=16896, padded to 18*1024
#define STAGEB 73728            // bytes per nt-stage: 4 experts * ESEC (=72 KiB)
#define LAYB   589824           // bytes per layer in W16 image: 8 nt-stages

typedef _Float16 half8  __attribute__((ext_vector_type(8)));   // 4 VGPRs
typedef _Float16 half2v __attribute__((ext_vector_type(2)));
typedef float    f32x4  __attribute__((ext_vector_type(4)));

// ---- W pre-pass: fp32 [e][k][n] -> fp16 staged image [L][nt][e][n_local][k] ----
// One thread per 16B output chunk (3 layers * 4 e * 32 k-chunks * 256 n = 98304).
// Reads coalesced along n; writes scattered 16B (1.5 MB total, negligible).
__global__ __launch_bounds__(256) void convert_w(
    const float* __restrict__ W1, const float* __restrict__ W2,
    const float* __restrict__ W3, char* __restrict__ W16T)
{
  const int g  = blockIdx.x * 256 + threadIdx.x;
  const int n  = g & 255;          // global output column
  const int k8 = (g >> 8) & 31;    // 16-byte k chunk (8 halves)
  const int e  = (g >> 13) & 3;
  const int L  = g >> 15;
  const float* WL  = (L == 0) ? W1 : (L == 1) ? W2 : W3;
  const float* src = WL + (size_t)e * DIM * DIM + (size_t)k8 * 8 * DIM + n;
  half8 h;
  #pragma unroll
  for (int j = 0; j < 8; ++j) h[j] = (_Float16)src[(size_t)j * DIM];
  *(half8*)(W16T + (size_t)L * LAYB + (size_t)(n >> 5) * STAGEB
            + e * ESEC + (n & 31) * ROWB + k8 * 16) = h;
}

// One cyclic-MoE layer: Out[b,:] = act( sum_e C[b,e]*(X[b,:] @ W_e + bias_e) )
// Restructured from the 617us version:
//   - block = 512 threads (8 waves), 256 rows; grid = 256 (exactly 1 block/CU).
//   - 8 phases (one per 32-col n-tile), each staging ALL 4 experts (72 KB) into
//     a double-buffered LDS image via global_load_lds dwordx4, prefetched
//     BEFORE computing the current tile (one barrier per phase, not 8).
//   - W pre-converted/pre-laid-out to fp16 by convert_w (WF16 path); fp32
//     fallback staging kept for tiny-workspace case.
//   - per-row mixing coefficients hoisted to registers (creg) after prologue.
template<bool WF16, bool IN_F16, bool OUT_F16, bool RELU>
__global__ __launch_bounds__(512, 2) void moe_layer(
    const void* __restrict__ Xin_,
    const float* __restrict__ phi,
    const float* __restrict__ Wf32,   // [4,256,256] fp32 (fallback path only)
    const char* __restrict__ W16,     // this layer's staged fp16 image (LAYB bytes)
    const float* __restrict__ bias,   // [4,256] fp32
    void* __restrict__ Out_,
    float acc_scale, float store_scale)
{
  __shared__ __attribute__((aligned(16))) char sStage[2][STAGEB];  // 2 x 72 KB
  __shared__ float sC[256][4];       // per-row expert coefficients
  __shared__ float sBias[4][DIM];

  const int tid  = threadIdx.x;
  const int row0 = blockIdx.x * 256;
  const int wave = tid >> 6;
  const int lane = tid & 63;
  const int quad = lane >> 4;
  const int l15  = lane & 15;

  // --- LAYOUT PROBE (proven in prior session): true (lane,reg)->(row,col) ---
  int rowId[4], colId[4];
  {
    half8 vone, vlan;
    #pragma unroll
    for (int j = 0; j < 8; ++j) {
      vone[j] = (_Float16)1.0f;
      vlan[j] = (_Float16)(float)l15;
    }
    const f32x4 z4 = {0.f, 0.f, 0.f, 0.f};
    const f32x4 pm = __builtin_amdgcn_mfma_f32_16x16x32_f16(vlan, vone, z4, 0, 0, 0);
    const f32x4 pn = __builtin_amdgcn_mfma_f32_16x16x32_f16(vone, vlan, z4, 0, 0, 0);
    #pragma unroll
    for (int r = 0; r < 4; ++r) {
      rowId[r] = ((int)(pm[r] * 0.03125f + 0.5f)) & 15;
      colId[r] = ((int)(pn[r] * 0.03125f + 0.5f)) & 15;
    }
  }

  // --- staging helper ---
  auto stage = [&](int buf, int nt_) {
    if constexpr (WF16) {
      // Pure async copy: wave w owns 9 KiB of the 72 KB image (linear).
      const char* g_ = W16 + (size_t)nt_ * STAGEB + wave * 9216 + lane * 16;
      char*       l_ = &sStage[buf][wave * 9216];
      #pragma unroll
      for (int j = 0; j < 9; ++j)
        __builtin_amdgcn_global_load_lds(
            (const __attribute__((address_space(1))) unsigned int*)(g_ + j * 1024),
            (__attribute__((address_space(3))) unsigned int*)(l_ + j * 1024),
            16, 0, 0);
    } else {
      // fp32 fallback: read W[e][k][n] float4 pairs, cvt, half2 LDS writes.
      char* sb = &sStage[buf][0];
      #pragma unroll
      for (int it = 0; it < 8; ++it) {
        const int p  = it * 512 + tid;       // 4096 (e, k-pair, n4) units
        const int e  = p >> 10;
        const int k2 = (p & 1023) >> 3;      // 0..127
        const int ng = p & 7;
        const float* Wp = Wf32 + (size_t)e * DIM * DIM
                        + (size_t)(k2 * 2) * DIM + nt_ * 32 + ng * 4;
        const float4 v0 = *(const float4*)Wp;
        const float4 v1 = *(const float4*)(Wp + DIM);
        const float s0[4] = {v0.x, v0.y, v0.z, v0.w};
        const float s1[4] = {v1.x, v1.y, v1.z, v1.w};
        #pragma unroll
        for (int j = 0; j < 4; ++j) {
          const int n = ng * 4 + j;
          half2v h;
          h[0] = (_Float16)s0[j];
          h[1] = (_Float16)s1[j];
          *(half2v*)(sb + e * ESEC + n * ROWB + k2 * 4) = h;
        }
      }
    }
  };

  // --- prologue: kick off first stage, coefficients, bias, A-fragments ---
  stage(0, 0);

  if (tid < 256) {
    const float w  = phi[row0 + tid] * (float)(2.0 / M_PI);  // [0,4]
    const int   wi = (int)w;                                 // trunc toward zero
    const float w2 = w * w, w3 = w2 * w;
    const float cf[4] = {
      -0.5f * w + w2 - 0.5f * w3,
      -2.5f * w2 + 1.5f * w3,
       0.5f * w + 2.0f * w2 - 1.5f * w3,
      -0.5f * w2 + 0.5f * w3 };
    #pragma unroll
    for (int e = 0; e < 4; ++e) sC[tid][e] = cf[(e + 1 - wi) & 3];
  }
  #pragma unroll
  for (int i = tid; i < 4 * DIM; i += 512) sBias[i >> 8][i & 255] = bias[i];

  // A fragments (fp16): wave owns 32 rows = 2 m-tiles x 8 k-chunks, in VGPRs.
  half8 afr[2][8];
  #pragma unroll
  for (int m = 0; m < 2; ++m) {
    const size_t row = (size_t)(row0 + wave * 32 + m * 16 + l15);
    if constexpr (IN_F16) {
      const _Float16* xr = (const _Float16*)Xin_ + row * DIM;
      #pragma unroll
      for (int kb = 0; kb < 8; ++kb)
        afr[m][kb] = *(const half8*)(xr + kb * 32 + quad * 8);
    } else {
      const float* xr = (const float*)Xin_ + row * DIM;
      #pragma unroll
      for (int kb = 0; kb < 8; ++kb) {
        const float4 a = *(const float4*)(xr + kb * 32 + quad * 8);
        const float4 b = *(const float4*)(xr + kb * 32 + quad * 8 + 4);
        half8 h;
        h[0] = (_Float16)a.x; h[1] = (_Float16)a.y;
        h[2] = (_Float16)a.z; h[3] = (_Float16)a.w;
        h[4] = (_Float16)b.x; h[5] = (_Float16)b.y;
        h[6] = (_Float16)b.z; h[7] = (_Float16)b.w;
        afr[m][kb] = h;
      }
    }
  }

  __syncthreads();   // stage(0) + sC + sBias ready

  // Per-row mixing coefficients in registers (kills 4*32 LDS reads per phase).
  float creg[2][4][4];
  #pragma unroll
  for (int m = 0; m < 2; ++m)
    #pragma unroll
    for (int r = 0; r < 4; ++r) {
      const int rl = wave * 32 + m * 16 + rowId[r];
      #pragma unroll
      for (int e = 0; e < 4; ++e) creg[m][r][e] = sC[rl][e];
    }

  // --- main loop: 8 n-tile phases, double-buffered ---
  int cur = 0;
  for (int nt = 0; nt < 8; ++nt) {
    if (nt < 7) stage(cur ^ 1, nt + 1);   // prefetch next tile (overlaps compute)

    const char* sb = &sStage[cur][0];
    float fin[2][2][4];
    #pragma unroll
    for (int m = 0; m < 2; ++m)
      #pragma unroll
      for (int t = 0; t < 2; ++t)
        #pragma unroll
        for (int r = 0; r < 4; ++r) fin[m][t][r] = 0.f;

    #pragma unroll
    for (int e = 0; e < 4; ++e) {
      f32x4 acc[2][2];
      #pragma unroll
      for (int m = 0; m < 2; ++m)
        #pragma unroll
        for (int t = 0; t < 2; ++t) acc[m][t] = (f32x4){0.f, 0.f, 0.f, 0.f};

      #pragma unroll
      for (int kb = 0; kb < 8; ++kb) {
        #pragma unroll
        for (int t = 0; t < 2; ++t) {
          const half8 b = *(const half8*)(sb + e * ESEC + (t * 16 + l15) * ROWB
                                          + kb * 64 + quad * 16);
          acc[0][t] = __builtin_amdgcn_mfma_f32_16x16x32_f16(afr[0][kb], b, acc[0][t], 0, 0, 0);
          acc[1][t] = __builtin_amdgcn_mfma_f32_16x16x32_f16(afr[1][kb], b, acc[1][t], 0, 0, 0);
        }
      }

      #pragma unroll
      for (int m = 0; m < 2; ++m)
        #pragma unroll
        for (int t = 0; t < 2; ++t)
          #pragma unroll
          for (int r = 0; r < 4; ++r)
            fin[m][t][r] += creg[m][r][e] * acc[m][t][r];
    }

    // --- epilogue for this n-tile ---
    #pragma unroll
    for (int t = 0; t < 2; ++t)
      #pragma unroll
      for (int r = 0; r < 4; ++r) {
        const int n_l = nt * 32 + t * 16 + colId[r];
        float be[4];
        #pragma unroll
        for (int e = 0; e < 4; ++e) be[e] = sBias[e][n_l];
        #pragma unroll
        for (int m = 0; m < 2; ++m) {
          const int row_l = wave * 32 + m * 16 + rowId[r];
          float v = acc_scale * fin[m][t][r];
          #pragma unroll
          for (int e = 0; e < 4; ++e) v += creg[m][r][e] * be[e];
          if (RELU) v = fmaxf(v, 0.f);
          v *= store_scale;
          const size_t idx = (size_t)(row0 + row_l) * DIM + n_l;
          if (OUT_F16) ((_Float16*)Out_)[idx] = (_Float16)v;
          else         ((float*)Out_)[idx] = v;
        }
      }

    __syncthreads();   // drains vmcnt: next buffer staged, this buffer free
    cur ^= 1;
  }
}

extern "C" void kernel_launch(void* const* d_in, const int* in_sizes, int n_in,
                              void* d_out, int out_size, void* d_ws, size_t ws_size,
                              hipStream_t stream) {
  const float* X   = (const float*)d_in[0];
  const float* phi = (const float*)d_in[1];
  const float* W1  = (const float*)d_in[2];
  const float* b1  = (const float*)d_in[3];
  const float* W2  = (const float*)d_in[4];
  const float* b2  = (const float*)d_in[5];
  const float* W3  = (const float*)d_in[6];
  const float* b3  = (const float*)d_in[7];

  // Buffer plan (R3/R5-proven):
  //   H1 fp16 (32 MB) -> lower half of d_out.
  //   H2 fp16 (32 MB) -> d_ws if it fits, else dead X buffer (restored by harness).
  //   W16 image (~1.7 MB) -> d_ws tail/head when room; else fp32 staging path.
  //   H2 stored pre-scaled by 1/8; layer 3 undoes (x8).
  const size_t h2_bytes  = (size_t)NB * DIM * sizeof(_Float16);
  const size_t w16_bytes = (size_t)3 * LAYB;

  _Float16* H1  = (_Float16*)d_out;
  _Float16* H2;
  char*     W16 = nullptr;
  if (ws_size >= h2_bytes + w16_bytes) {
    H2  = (_Float16*)d_ws;
    W16 = (char*)d_ws + h2_bytes;
  } else if (ws_size >= h2_bytes) {
    H2 = (_Float16*)d_ws;                 // no W16 room -> fp32 staging
  } else if (ws_size >= w16_bytes) {
    W16 = (char*)d_ws;
    H2  = (_Float16*)d_in[0];
  } else {
    H2 = (_Float16*)d_in[0];
  }
  float* out = (float*)d_out;

  dim3 grid(NB / 256);
  dim3 block(512);

  if (W16) {
    convert_w<<<dim3(384), dim3(256), 0, stream>>>(W1, W2, W3, W16);
    moe_layer<true, false, true,  true ><<<grid, block, 0, stream>>>(X,  phi, nullptr, W16,            b1, H1,  1.0f, 1.0f);
    moe_layer<true, true,  true,  true ><<<grid, block, 0, stream>>>(H1, phi, nullptr, W16 + LAYB,     b2, H2,  1.0f, 0.125f);
    moe_layer<true, true,  false, false><<<grid, block, 0, stream>>>(H2, phi, nullptr, W16 + 2 * LAYB, b3, out, 8.0f, 1.0f);
  } else {
    moe_layer<false, false, true,  true ><<<grid, block, 0, stream>>>(X,  phi, W1, nullptr, b1, H1,  1.0f, 1.0f);
    moe_layer<false, true,  true,  true ><<<grid, block, 0, stream>>>(H1, phi, W2, nullptr, b2, H2,  1.0f, 0.125f);
    moe_layer<false, true,  false, false><<<grid, block, 0, stream>>>(H2, phi, W3, nullptr, b3, out, 8.0f, 1.0f);
  }
}

// Round 2
// 241.741 us; speedup vs baseline: 2.5985x; 1.0304x over previous
//
#include <hip/hip_runtime.h>
#include <math.h>

#define NB 65536
#define DIM 256

// Staged-W geometry (fp16, padded-linear k-rows).
// ROWB = 264 halves = 528 B = 33*16B: ds_read_b128-aligned, start banks spread
// uniformly across lanes (8 lanes per 16B slot = structural minimum).
// Phase tile = 16 cols x 4 experts = 33792 B, padded to 36864 (9 KiB/wave,
// 9 x 16B global_load_lds per lane with 256-thread blocks).
#define ROWB   528              // bytes per k-row (K=256 halves + 8 pad halves)
#define ESEC   9216             // bytes per expert section: 16*528=8448, padded to 9*1024
#define STAGEB 36864            // bytes per nt-stage: 4 experts * ESEC (=36 KiB)
#define NTILE  16               // phases per layer (16 cols each)
#define LAYB   589824           // bytes per layer in W16 image: 16 nt-stages

typedef _Float16 half8  __attribute__((ext_vector_type(8)));   // 4 VGPRs
typedef _Float16 half2v __attribute__((ext_vector_type(2)));
typedef float    f32x4  __attribute__((ext_vector_type(4)));

// ---- W pre-pass: fp32 [e][k][n] -> fp16 staged image [L][nt16][e][n16][k] ----
// One thread per 16B output chunk (3 layers * 4 e * 32 k-chunks * 256 n = 98304).
__global__ __launch_bounds__(256) void convert_w(
    const float* __restrict__ W1, const float* __restrict__ W2,
    const float* __restrict__ W3, char* __restrict__ W16T)
{
  const int g  = blockIdx.x * 256 + threadIdx.x;
  const int n  = g & 255;          // global output column
  const int k8 = (g >> 8) & 31;    // 16-byte k chunk (8 halves)
  const int e  = (g >> 13) & 3;
  const int L  = g >> 15;
  const float* WL  = (L == 0) ? W1 : (L == 1) ? W2 : W3;
  const float* src = WL + (size_t)e * DIM * DIM + (size_t)k8 * 8 * DIM + n;
  half8 h;
  #pragma unroll
  for (int j = 0; j < 8; ++j) h[j] = (_Float16)src[(size_t)j * DIM];
  *(half8*)(W16T + (size_t)L * LAYB + (size_t)(n >> 4) * STAGEB
            + e * ESEC + (n & 15) * ROWB + k8 * 16) = h;
}

// One cyclic-MoE layer: Out[b,:] = act( sum_e C[b,e]*(X[b,:] @ W_e + bias_e) )
// R2 restructure (from the 249us version): TWO independent barrier groups/CU.
//   - block = 256 threads (4 waves), 128 rows; grid = 512 -> 2 blocks/CU.
//   - 16 phases (one per 16-col n-tile), each staging all 4 experts (36 KB)
//     into double-buffered LDS via global_load_lds dwordx4, prefetched before
//     computing the current tile. LDS/block = 78 KB so two blocks co-reside;
//     while one block drains its barrier/vmcnt, the other issues MFMA.
//   - everything else (probe, afr, creg, bank-spread ROWB) proven unchanged.
template<bool WF16, bool IN_F16, bool OUT_F16, bool RELU>
__global__ __launch_bounds__(256, 2) void moe_layer(
    const void* __restrict__ Xin_,
    const float* __restrict__ phi,
    const float* __restrict__ Wf32,   // [4,256,256] fp32 (fallback path only)
    const char* __restrict__ W16,     // this layer's staged fp16 image (LAYB bytes)
    const float* __restrict__ bias,   // [4,256] fp32
    void* __restrict__ Out_,
    float acc_scale, float store_scale)
{
  __shared__ __attribute__((aligned(16))) char sStage[2][STAGEB];  // 2 x 36 KB
  __shared__ float sC[128][4];       // per-row expert coefficients
  __shared__ float sBias[4][DIM];

  const int tid  = threadIdx.x;
  const int row0 = blockIdx.x * 128;
  const int wave = tid >> 6;
  const int lane = tid & 63;
  const int quad = lane >> 4;
  const int l15  = lane & 15;

  // --- LAYOUT PROBE (proven): true (lane,reg)->(row,col) ---
  int rowId[4], colId[4];
  {
    half8 vone, vlan;
    #pragma unroll
    for (int j = 0; j < 8; ++j) {
      vone[j] = (_Float16)1.0f;
      vlan[j] = (_Float16)(float)l15;
    }
    const f32x4 z4 = {0.f, 0.f, 0.f, 0.f};
    const f32x4 pm = __builtin_amdgcn_mfma_f32_16x16x32_f16(vlan, vone, z4, 0, 0, 0);
    const f32x4 pn = __builtin_amdgcn_mfma_f32_16x16x32_f16(vone, vlan, z4, 0, 0, 0);
    #pragma unroll
    for (int r = 0; r < 4; ++r) {
      rowId[r] = ((int)(pm[r] * 0.03125f + 0.5f)) & 15;
      colId[r] = ((int)(pn[r] * 0.03125f + 0.5f)) & 15;
    }
  }

  // --- staging helper ---
  auto stage = [&](int buf, int nt_) {
    if constexpr (WF16) {
      // Pure async copy: wave w owns 9 KiB of the 36 KB tile (linear).
      const char* g_ = W16 + (size_t)nt_ * STAGEB + wave * 9216 + lane * 16;
      char*       l_ = &sStage[buf][wave * 9216];
      #pragma unroll
      for (int j = 0; j < 9; ++j)
        __builtin_amdgcn_global_load_lds(
            (const __attribute__((address_space(1))) unsigned int*)(g_ + j * 1024),
            (__attribute__((address_space(3))) unsigned int*)(l_ + j * 1024),
            16, 0, 0);
    } else {
      // fp32 fallback: read W[e][k][n] float2 pairs, cvt, half2 LDS writes.
      char* sb = &sStage[buf][0];
      #pragma unroll
      for (int it = 0; it < 16; ++it) {
        const int p   = it * 256 + tid;      // 4096 (e, k-pair, col-pair) units
        const int e   = p >> 10;
        const int rem = p & 1023;
        const int k2  = rem >> 3;            // 0..127
        const int ng  = rem & 7;             // col pair 0..7
        const float* Wp = Wf32 + (size_t)e * DIM * DIM
                        + (size_t)(k2 * 2) * DIM + nt_ * 16 + ng * 2;
        const float2 v0 = *(const float2*)Wp;
        const float2 v1 = *(const float2*)(Wp + DIM);
        const float s0[2] = {v0.x, v0.y};
        const float s1[2] = {v1.x, v1.y};
        #pragma unroll
        for (int j = 0; j < 2; ++j) {
          half2v h;
          h[0] = (_Float16)s0[j];
          h[1] = (_Float16)s1[j];
          *(half2v*)(sb + e * ESEC + (ng * 2 + j) * ROWB + k2 * 4) = h;
        }
      }
    }
  };

  // --- prologue: kick off first stage, coefficients, bias, A-fragments ---
  stage(0, 0);

  if (tid < 128) {
    const float w  = phi[row0 + tid] * (float)(2.0 / M_PI);  // [0,4]
    const int   wi = (int)w;                                 // trunc toward zero
    const float w2 = w * w, w3 = w2 * w;
    const float cf[4] = {
      -0.5f * w + w2 - 0.5f * w3,
      -2.5f * w2 + 1.5f * w3,
       0.5f * w + 2.0f * w2 - 1.5f * w3,
      -0.5f * w2 + 0.5f * w3 };
    #pragma unroll
    for (int e = 0; e < 4; ++e) sC[tid][e] = cf[(e + 1 - wi) & 3];
  }
  #pragma unroll
  for (int i = tid; i < 4 * DIM; i += 256) sBias[i >> 8][i & 255] = bias[i];

  // A fragments (fp16): wave owns 32 rows = 2 m-tiles x 8 k-chunks, in VGPRs.
  half8 afr[2][8];
  #pragma unroll
  for (int m = 0; m < 2; ++m) {
    const size_t row = (size_t)(row0 + wave * 32 + m * 16 + l15);
    if constexpr (IN_F16) {
      const _Float16* xr = (const _Float16*)Xin_ + row * DIM;
      #pragma unroll
      for (int kb = 0; kb < 8; ++kb)
        afr[m][kb] = *(const half8*)(xr + kb * 32 + quad * 8);
    } else {
      const float* xr = (const float*)Xin_ + row * DIM;
      #pragma unroll
      for (int kb = 0; kb < 8; ++kb) {
        const float4 a = *(const float4*)(xr + kb * 32 + quad * 8);
        const float4 b = *(const float4*)(xr + kb * 32 + quad * 8 + 4);
        half8 h;
        h[0] = (_Float16)a.x; h[1] = (_Float16)a.y;
        h[2] = (_Float16)a.z; h[3] = (_Float16)a.w;
        h[4] = (_Float16)b.x; h[5] = (_Float16)b.y;
        h[6] = (_Float16)b.z; h[7] = (_Float16)b.w;
        afr[m][kb] = h;
      }
    }
  }

  __syncthreads();   // stage(0) + sC + sBias ready

  // Per-row mixing coefficients in registers.
  float creg[2][4][4];
  #pragma unroll
  for (int m = 0; m < 2; ++m)
    #pragma unroll
    for (int r = 0; r < 4; ++r) {
      const int rl = wave * 32 + m * 16 + rowId[r];
      #pragma unroll
      for (int e = 0; e < 4; ++e) creg[m][r][e] = sC[rl][e];
    }

  // --- main loop: 16 n-tile phases, double-buffered ---
  int cur = 0;
  for (int nt = 0; nt < NTILE; ++nt) {
    if (nt < NTILE - 1) stage(cur ^ 1, nt + 1);  // prefetch next tile

    const char* sb = &sStage[cur][0];
    float fin[2][4];
    #pragma unroll
    for (int m = 0; m < 2; ++m)
      #pragma unroll
      for (int r = 0; r < 4; ++r) fin[m][r] = 0.f;

    #pragma unroll
    for (int e = 0; e < 4; ++e) {
      f32x4 acc[2];
      acc[0] = (f32x4){0.f, 0.f, 0.f, 0.f};
      acc[1] = (f32x4){0.f, 0.f, 0.f, 0.f};

      #pragma unroll
      for (int kb = 0; kb < 8; ++kb) {
        const half8 b = *(const half8*)(sb + e * ESEC + l15 * ROWB
                                        + kb * 64 + quad * 16);
        acc[0] = __builtin_amdgcn_mfma_f32_16x16x32_f16(afr[0][kb], b, acc[0], 0, 0, 0);
        acc[1] = __builtin_amdgcn_mfma_f32_16x16x32_f16(afr[1][kb], b, acc[1], 0, 0, 0);
      }

      #pragma unroll
      for (int m = 0; m < 2; ++m)
        #pragma unroll
        for (int r = 0; r < 4; ++r)
          fin[m][r] += creg[m][r][e] * acc[m][r];
    }

    // --- epilogue for this n-tile ---
    #pragma unroll
    for (int r = 0; r < 4; ++r) {
      const int n_l = nt * 16 + colId[r];
      float be[4];
      #pragma unroll
      for (int e = 0; e < 4; ++e) be[e] = sBias[e][n_l];
      #pragma unroll
      for (int m = 0; m < 2; ++m) {
        const int row_l = wave * 32 + m * 16 + rowId[r];
        float v = acc_scale * fin[m][r];
        #pragma unroll
        for (int e = 0; e < 4; ++e) v += creg[m][r][e] * be[e];
        if (RELU) v = fmaxf(v, 0.f);
        v *= store_scale;
        const size_t idx = (size_t)(row0 + row_l) * DIM + n_l;
        if (OUT_F16) ((_Float16*)Out_)[idx] = (_Float16)v;
        else         ((float*)Out_)[idx] = v;
      }
    }

    __syncthreads();   // prefetched buffer complete; current buffer free
    cur ^= 1;
  }
}

extern "C" void kernel_launch(void* const* d_in, const int* in_sizes, int n_in,
                              void* d_out, int out_size, void* d_ws, size_t ws_size,
                              hipStream_t stream) {
  const float* X   = (const float*)d_in[0];
  const float* phi = (const float*)d_in[1];
  const float* W1  = (const float*)d_in[2];
  const float* b1  = (const float*)d_in[3];
  const float* W2  = (const float*)d_in[4];
  const float* b2  = (const float*)d_in[5];
  const float* W3  = (const float*)d_in[6];
  const float* b3  = (const float*)d_in[7];

  // Buffer plan (proven):
  //   H1 fp16 (32 MB) -> lower half of d_out.
  //   H2 fp16 (32 MB) -> d_ws if it fits, else dead X buffer (restored by harness).
  //   W16 image (~1.7 MB) -> d_ws tail when room; else fp32 staging path.
  //   H2 stored pre-scaled by 1/8; layer 3 undoes (x8).
  const size_t h2_bytes  = (size_t)NB * DIM * sizeof(_Float16);
  const size_t w16_bytes = (size_t)3 * LAYB;

  _Float16* H1  = (_Float16*)d_out;
  _Float16* H2;
  char*     W16 = nullptr;
  if (ws_size >= h2_bytes + w16_bytes) {
    H2  = (_Float16*)d_ws;
    W16 = (char*)d_ws + h2_bytes;
  } else if (ws_size >= h2_bytes) {
    H2 = (_Float16*)d_ws;                 // no W16 room -> fp32 staging
  } else if (ws_size >= w16_bytes) {
    W16 = (char*)d_ws;
    H2  = (_Float16*)d_in[0];
  } else {
    H2 = (_Float16*)d_in[0];
  }
  float* out = (float*)d_out;

  dim3 grid(NB / 128);
  dim3 block(256);

  if (W16) {
    convert_w<<<dim3(384), dim3(256), 0, stream>>>(W1, W2, W3, W16);
    moe_layer<true, false, true,  true ><<<grid, block, 0, stream>>>(X,  phi, nullptr, W16,            b1, H1,  1.0f, 1.0f);
    moe_layer<true, true,  true,  true ><<<grid, block, 0, stream>>>(H1, phi, nullptr, W16 + LAYB,     b2, H2,  1.0f, 0.125f);
    moe_layer<true, true,  false, false><<<grid, block, 0, stream>>>(H2, phi, nullptr, W16 + 2 * LAYB, b3, out, 8.0f, 1.0f);
  } else {
    moe_layer<false, false, true,  true ><<<grid, block, 0, stream>>>(X,  phi, W1, nullptr, b1, H1,  1.0f, 1.0f);
    moe_layer<false, true,  true,  true ><<<grid, block, 0, stream>>>(H1, phi, W2, nullptr, b2, H2,  1.0f, 0.125f);
    moe_layer<false, true,  false, false><<<grid, block, 0, stream>>>(H2, phi, W3, nullptr, b3, out, 8.0f, 1.0f);
  }
}